// Round 13
// baseline (101.111 us; speedup 1.0000x reference)
//
#include <hip/hip_runtime.h>
#include <hip/hip_bf16.h>

#define NODES   50000
#define EDGES   1600000
#define DIM     128
#define NB      391        // buckets of 128 nodes
#define BSTRIDE 4608       // fixed bucket capacity (mean 4092, +8 sigma)
#define TILE    8192
#define EPT     32
#define NTILES  196
#define ZROW    50000      // zero sentinel row in y2 (rows 50000..50047 zeroed by gemm)

typedef unsigned int   u32;
typedef unsigned short u16;
typedef __attribute__((ext_vector_type(4))) float f32x4;
typedef __attribute__((ext_vector_type(8))) short s16x8;

__device__ inline u16 f2bf(float f) {
  __hip_bfloat16 h = __float2bfloat16(f);
  return *reinterpret_cast<u16*>(&h);
}

// ---------------- W -> WT bf16 pre-swizzled + gcursor init (fused) ----------------
__global__ __launch_bounds__(256) void k_prep(const float* __restrict__ W,
                                              u16* __restrict__ wts,
                                              int* __restrict__ gcursor) {
  __shared__ float T[32 * 132];
  int t = threadIdx.x;
  int gi = blockIdx.x * 256 + t;
  if (gi < NB) gcursor[gi] = gi * BSTRIDE;
  int c0 = blockIdx.x * 32;
#pragma unroll
  for (int i = 0; i < 16; ++i) {
    int idx = i * 256 + t;            // 4096 = 128k x 32c
    int k = idx >> 5;
    int cc = idx & 31;
    T[cc * 132 + k] = W[k * 128 + c0 + cc];
  }
  __syncthreads();
#pragma unroll
  for (int i = 0; i < 2; ++i) {
    int idx = i * 256 + t;            // 512 = 32c x 16 chunks
    int cc = idx >> 4;
    int kc = idx & 15;
    int c = c0 + cc;
    int kbase = kc * 8;
    u32 p[4];
#pragma unroll
    for (int u = 0; u < 4; ++u) {
      float a = T[cc * 132 + kbase + 2 * u];
      float b = T[cc * 132 + kbase + 2 * u + 1];
      p[u] = (u32)f2bf(a) | ((u32)f2bf(b) << 16);
    }
    int off = c * 256 + ((kbase * 2) ^ ((c & 15) << 4));
    *(uint4*)((char*)wts + off) = make_uint4(p[0], p[1], p[2], p[3]);
  }
}

// ---------------- bin pass A: edges -> bucket regions (r,c packed u32), int4 loads ----------------
__global__ __launch_bounds__(256) void k_binA(const int* __restrict__ erow,
                                              const int* __restrict__ ecol,
                                              int* __restrict__ gcursor,
                                              u32* __restrict__ binned) {
  __shared__ int hist[NB];
  __shared__ int lcur[NB];
  int t = threadIdx.x;
  for (int b = t; b < NB; b += 256) hist[b] = 0;
  __syncthreads();
  int base = blockIdx.x * TILE;
  u32 v[EPT];
#pragma unroll
  for (int k = 0; k < 8; ++k) {
    int e4 = base + k * 1024 + t * 4;   // EDGES % 4 == 0 -> full int4 in-bounds when e4 < EDGES
    if (e4 < EDGES) {
      int4 rr = *(const int4*)&erow[e4];
      int4 cc = *(const int4*)&ecol[e4];
      v[k * 4 + 0] = ((u32)rr.x << 16) | (u32)cc.x;
      v[k * 4 + 1] = ((u32)rr.y << 16) | (u32)cc.y;
      v[k * 4 + 2] = ((u32)rr.z << 16) | (u32)cc.z;
      v[k * 4 + 3] = ((u32)rr.w << 16) | (u32)cc.w;
      atomicAdd(&hist[(u32)rr.x >> 7], 1);
      atomicAdd(&hist[(u32)rr.y >> 7], 1);
      atomicAdd(&hist[(u32)rr.z >> 7], 1);
      atomicAdd(&hist[(u32)rr.w >> 7], 1);
    } else {
      v[k * 4 + 0] = 0xffffffffu;
      v[k * 4 + 1] = 0xffffffffu;
      v[k * 4 + 2] = 0xffffffffu;
      v[k * 4 + 3] = 0xffffffffu;
    }
  }
  __syncthreads();
  for (int b = t; b < NB; b += 256) {
    int h = hist[b];
    lcur[b] = h ? atomicAdd(&gcursor[b], h) : 0;
  }
  __syncthreads();
#pragma unroll
  for (int k = 0; k < EPT; ++k) {
    if (v[k] != 0xffffffffu) {
      int b = (int)(v[k] >> 23);
      int pos = atomicAdd(&lcur[b], 1);
      if (pos < (b + 1) * BSTRIDE) binned[pos] = v[k];   // overflow clamp (never hit)
    }
  }
}

// ---------------- bin pass B: single read, LDS-staged node sort, coalesced cols write ----------------
__global__ __launch_bounds__(256) void k_binB(const u32* __restrict__ binned,
                                              const int* __restrict__ gcur,
                                              int2* __restrict__ rp2,
                                              float* __restrict__ dis,
                                              u16* __restrict__ cols) {
  __shared__ int cnt[128];
  __shared__ int sc[128];
  __shared__ int lcur[128];
  __shared__ u16 stage[BSTRIDE];     // 9216 B
  int b = blockIdx.x;
  int t = threadIdx.x;
  int n0 = b << 7;
  int s = b * BSTRIDE;
  int e = gcur[b];
  if (e > s + BSTRIDE) e = s + BSTRIDE;
  int cntE = e - s;
  if (t < 128) cnt[t] = 0;
  __syncthreads();
  // hold this thread's edges in registers (static indices), count per node
  u32 held[18];                      // BSTRIDE/256 = 18
#pragma unroll
  for (int k = 0; k < 18; ++k) {
    int j = s + t + k * 256;
    u32 v = (j < e) ? binned[j] : 0xffffffffu;   // r<50000 -> top half never 0xffff
    held[k] = v;
    if (v != 0xffffffffu) atomicAdd(&cnt[(int)(v >> 16) - n0], 1);
  }
  __syncthreads();
  if (t < 128) sc[t] = cnt[t];
  __syncthreads();
  for (int off = 1; off < 128; off <<= 1) {
    int tmp = (t >= off && t < 128) ? sc[t - off] : 0;
    __syncthreads();
    if (t < 128) sc[t] += tmp;
    __syncthreads();
  }
  if (t < 128) {
    int n = n0 + t;
    if (n < NODES) {
      int lexcl = sc[t] - cnt[t];              // local (within bucket)
      rp2[n] = make_int2(s + lexcl, s + lexcl + cnt[t]);
      lcur[t] = lexcl;
      dis[n] = rsqrtf((float)cnt[t]);
    }
  }
  __syncthreads();
#pragma unroll
  for (int k = 0; k < 18; ++k) {
    u32 v = held[k];
    if (v != 0xffffffffu) {
      int pos = atomicAdd(&lcur[(int)(v >> 16) - n0], 1);
      stage[pos] = (u16)(v & 0xffffu);
    }
  }
  __syncthreads();
  // coalesced copy stage[0..cntE) -> cols[s..); one extra u16 into the unused gap is harmless
  {
    u32* dst = (u32*)(cols + s);               // s even -> 4B aligned
    const u32* src = (const u32*)stage;
    int nw = (cntE + 1) >> 1;
    for (int i = t; i < nw; i += 256) dst[i] = src[i];
  }
}

// ---------------- y2 = diag(dis) * (x @ W) via MFMA, stored bf16 (pad rows zeroed) ----------------
__global__ __launch_bounds__(256) void k_gemm(const float* __restrict__ x,
                                              const u16* __restrict__ wts,
                                              const float* __restrict__ dis,
                                              u16* __restrict__ y2) {
  __shared__ u16 xs[64 * 128];
  __shared__ u16 ws[128 * 128];
  const int t = threadIdx.x;
  const int bb = blockIdx.x * 64;

  {
    const uint4* src = (const uint4*)wts;
    uint4* dst = (uint4*)ws;
#pragma unroll
    for (int i = 0; i < 8; ++i) dst[i * 256 + t] = src[i * 256 + t];
  }
  {
#pragma unroll
    for (int i = 0; i < 8; ++i) {
      int goff = i * 4096 + t * 16;
      int row = goff >> 9;
      int gr = bb + row;
      float4 v = make_float4(0.f, 0.f, 0.f, 0.f);
      if (gr < NODES) v = *(const float4*)((const char*)x + (size_t)gr * 512 + (goff & 511));
      u32 lo = (u32)f2bf(v.x) | ((u32)f2bf(v.y) << 16);
      u32 hi = (u32)f2bf(v.z) | ((u32)f2bf(v.w) << 16);
      int colb = (goff & 511) >> 1;
      int off = row * 256 + (colb ^ ((row & 15) << 4));
      *(uint2*)((char*)xs + off) = make_uint2(lo, hi);
    }
  }
  __syncthreads();

  const int w = t >> 6, l = t & 63, m = l & 15, g = l >> 4;
  f32x4 acc[8];
#pragma unroll
  for (int j = 0; j < 8; ++j) acc[j] = (f32x4)0.0f;

  const char* xb = (const char*)xs;
  const char* wb = (const char*)ws;
  const int arow = w * 16 + m;
#pragma unroll
  for (int s = 0; s < 4; ++s) {
    int kx = (g * 16 + s * 64) ^ (m << 4);
    s16x8 a = *(const s16x8*)(xb + arow * 256 + kx);
#pragma unroll
    for (int j = 0; j < 8; ++j) {
      s16x8 b = *(const s16x8*)(wb + (j * 16 + m) * 256 + kx);
      acc[j] = __builtin_amdgcn_mfma_f32_16x16x32_bf16(a, b, acc[j], 0, 0, 0);
    }
  }

  // epilogue: scale by dis[row]; rows >= NODES (up to 50047) store ZERO -> zero sentinel rows
  int rbase = bb + w * 16 + g * 4;
  float4 d4 = *(const float4*)&dis[rbase];   // dis region padded past 50000 (garbage ok, masked below)
#pragma unroll
  for (int j = 0; j < 8; ++j) {
#pragma unroll
    for (int r = 0; r < 4; ++r) {
      int gr = rbase + r;
      float dv = (r == 0) ? d4.x : (r == 1) ? d4.y : (r == 2) ? d4.z : d4.w;
      float val = (gr < NODES) ? acc[j][r] * dv : 0.0f;
      y2[(size_t)gr * 128 + j * 16 + m] = f2bf(val);   // gr <= 50047 < 50048 rows: in-bounds
    }
  }
}

// ---------------- aggregation: 32 edges in flight (4 groups x 8-deep), shfl-distributed cols ----------------
__global__ __launch_bounds__(256) void k_agg(const u16* __restrict__ y2,
                                             const int2* __restrict__ rp2,
                                             const u16* __restrict__ cols,
                                             const float* __restrict__ dis,
                                             const float* __restrict__ bias,
                                             float* __restrict__ out) {
  int node = (blockIdx.x * 256 + threadIdx.x) >> 6;
  int l = threadIdx.x & 63;
  if (node >= NODES) return;
  int q = l >> 4;          // edge-slot quarter
  int m = l & 15;          // 16B chunk within the 256B row
  int2 rr = rp2[node];
  int s = rr.x;
  int e = rr.y;

  float a0 = 0.f, a1 = 0.f, a2 = 0.f, a3 = 0.f;
  float a4 = 0.f, a5 = 0.f, a6 = 0.f, a7 = 0.f;
  const uint4* yb = (const uint4*)y2;
  const u32* cols32 = (const u32*)cols;
  const int hi = q & 1;             // halfword parity of (q + 4k)
  const int wbase = q >> 1;         // word index = wbase + 2k

  // bulk-load cols for the first 32-edge batch: lanes 0..15 hold words s/2 .. s/2+15
  // (s is even: bucket base + even local offsets... s = bucket_base + lexcl; lexcl may be odd!)
  // -> use word-aligned base: wb0 = s >> 1, with a +1 correction when s is odd.
  // To keep it simple and correct for odd s, fall back to per-col scalar loads when s is odd.
  u32 w0 = cols32[(s >> 1) + m];                 // covers cols[2*(s>>1) .. +32)
  int odd = s & 1;

#define COLAT(base, kk) /* col index base + q + 4*kk, sanitized */                      \
    (((base) + q + 4 * (kk) < e)                                                        \
       ? ((odd ? ((((base) + q + 4 * (kk)) & 1)                                         \
                    ? (__shfl(w0_cur, ((((base) + q + 4 * (kk)) - b0) >> 1)) & 0xffffu) \
                    : (__shfl(w0_cur, ((((base) + q + 4 * (kk)) - b0) >> 1)) >> 16))    \
                : 0)) : 0)

  // The macro above is unwieldy for odd s; use straightforward per-batch code instead:
  int c0, c1, c2, c3, c4, c5, c6, c7;
  {
    int b0 = (s >> 1) * 2;                       // even base covered by w0 words
#define GETC(kk, dst)  {                                                        \
      int idx = s + q + 4 * (kk);                                               \
      if (idx < e) {                                                            \
        int rel = idx - b0;      /* 0..32 (+1 if s odd) */                      \
        u32 wv = __shfl(w0, rel >> 1);                                          \
        dst = (rel & 1) ? (int)(wv >> 16) : (int)(wv & 0xffffu);                \
      } else dst = ZROW; }
    GETC(0, c0) GETC(1, c1) GETC(2, c2) GETC(3, c3)
    GETC(4, c4) GETC(5, c5) GETC(6, c6) GETC(7, c7)
#undef GETC
    // rel can reach 32 (s odd, kk=7,q=3 -> idx-b0 = 32) -> word 16: reload guard
    // handled because __shfl(w0,16) with lane 16 holds cols32[(s>>1)+16]? lanes 16..63
    // loaded m=l&15 -> lane 16's w0 = cols32[(s>>1)+0]. Avoid: clamp via scalar fix-up.
    if (odd) {
      // scalar fix-up for the one possibly-wrong slot (rel==32 maps wrong): q==3,k==7
      if (q == 3) { int idx = s + q + 28; c7 = (idx < e) ? (int)cols[idx] : ZROW; }
    }
  }

  for (int jb = s; jb < e; jb += 32) {
    int nb = jb + 32;
    u32 wn = cols32[(nb >> 1) + m];
    int d0, d1, d2, d3, d4x, d5, d6, d7;
    {
      int b0 = (nb >> 1) * 2;
#define GETC(kk, dst)  {                                                        \
      int idx = nb + q + 4 * (kk);                                              \
      if (idx < e) {                                                            \
        int rel = idx - b0;                                                     \
        u32 wv = __shfl(wn, rel >> 1);                                          \
        dst = (rel & 1) ? (int)(wv >> 16) : (int)(wv & 0xffffu);                \
      } else dst = ZROW; }
      GETC(0, d0) GETC(1, d1) GETC(2, d2) GETC(3, d3)
      GETC(4, d4x) GETC(5, d5) GETC(6, d6) GETC(7, d7)
#undef GETC
      if (odd && q == 3) { int idx = nb + 31; d7 = (idx < e) ? (int)cols[idx] : ZROW; }
    }
    uint4 v0 = yb[c0 * 16 + m];
    uint4 v1 = yb[c1 * 16 + m];
    uint4 v2 = yb[c2 * 16 + m];
    uint4 v3 = yb[c3 * 16 + m];
    uint4 v4 = yb[c4 * 16 + m];
    uint4 v5 = yb[c5 * 16 + m];
    uint4 v6 = yb[c6 * 16 + m];
    uint4 v7 = yb[c7 * 16 + m];
#define ACC(v)                                   \
    a0 += __uint_as_float((v).x << 16);          \
    a1 += __uint_as_float((v).x & 0xffff0000u);  \
    a2 += __uint_as_float((v).y << 16);          \
    a3 += __uint_as_float((v).y & 0xffff0000u);  \
    a4 += __uint_as_float((v).z << 16);          \
    a5 += __uint_as_float((v).z & 0xffff0000u);  \
    a6 += __uint_as_float((v).w << 16);          \
    a7 += __uint_as_float((v).w & 0xffff0000u);
    ACC(v0) ACC(v1) ACC(v2) ACC(v3) ACC(v4) ACC(v5) ACC(v6) ACC(v7)
#undef ACC
    c0 = d0; c1 = d1; c2 = d2; c3 = d3;
    c4 = d4x; c5 = d5; c6 = d6; c7 = d7;
    w0 = wn;
  }

  // reduce across the 4 groups (lane bits 4,5)
  a0 += __shfl_xor(a0, 16); a0 += __shfl_xor(a0, 32);
  a1 += __shfl_xor(a1, 16); a1 += __shfl_xor(a1, 32);
  a2 += __shfl_xor(a2, 16); a2 += __shfl_xor(a2, 32);
  a3 += __shfl_xor(a3, 16); a3 += __shfl_xor(a3, 32);
  a4 += __shfl_xor(a4, 16); a4 += __shfl_xor(a4, 32);
  a5 += __shfl_xor(a5, 16); a5 += __shfl_xor(a5, 32);
  a6 += __shfl_xor(a6, 16); a6 += __shfl_xor(a6, 32);
  a7 += __shfl_xor(a7, 16); a7 += __shfl_xor(a7, 32);

  float di = (e > s) ? dis[node] : 0.0f;
  if (q < 2) {
    float r0 = q ? a4 : a0;
    float r1 = q ? a5 : a1;
    float r2 = q ? a6 : a2;
    float r3 = q ? a7 : a3;
    float4 bb = *(const float4*)&bias[m * 8 + q * 4];
    f32x4 o;
    o[0] = bb.x + di * r0;
    o[1] = bb.y + di * r1;
    o[2] = bb.z + di * r2;
    o[3] = bb.w + di * r3;
    __builtin_nontemporal_store(o, (f32x4*)&out[(size_t)node * 128 + m * 8 + q * 4]);
  }
}

extern "C" void kernel_launch(void* const* d_in, const int* in_sizes, int n_in,
                              void* d_out, int out_size, void* d_ws, size_t ws_size,
                              hipStream_t stream) {
  const float* x    = (const float*)d_in[0];
  const float* W    = (const float*)d_in[1];
  const float* bias = (const float*)d_in[2];
  const int*   erow = (const int*)d_in[3];
  const int*   ecol = (const int*)d_in[4];
  float* out = (float*)d_out;

  char* ws = (char*)d_ws;
  int*   gcursor = (int*)(ws + 0);          // 1.6 KB
  int2*  rp2     = (int2*)(ws + 4096);      // 400 KB
  float* dis     = (float*)(ws + 409600);   // 200 KB (+pad, gemm reads to 50048)
  u16*   wts     = (u16*)(ws + 614400);     // 32 KB
  u32*   binned  = (u32*)(ws + 655360);     // 391*4608*4 = 7,206,912 B
  u16*   cols    = (u16*)(ws + 7864320);    // 391*4608*2 = 3,603,456 B (+1KB slack)
  u16*   y2      = (u16*)(ws + 11468800);   // 50048 rows * 256 B = 12,812,288 B

  k_prep<<<4, 256, 0, stream>>>(W, wts, gcursor);
  k_binA<<<NTILES, 256, 0, stream>>>(erow, ecol, gcursor, binned);
  k_binB<<<NB, 256, 0, stream>>>(binned, gcursor, rp2, dis, cols);
  k_gemm<<<(NODES + 63) / 64, 256, 0, stream>>>(x, wts, dis, y2);
  k_agg<<<(NODES * 64 + 255) / 256, 256, 0, stream>>>(y2, rp2, cols, dis, bias, out);
}

// Round 14
// 93.855 us; speedup vs baseline: 1.0773x; 1.0773x over previous
//
#include <hip/hip_runtime.h>
#include <hip/hip_bf16.h>

#define NODES   50000
#define EDGES   1600000
#define DIM     128
#define NB      391        // buckets of 128 nodes
#define BSTRIDE 4608       // fixed bucket capacity (mean 4092, +8 sigma)
#define TILE    8192
#define EPT     32
#define NTILES  196
#define ZROW    50000      // zero sentinel row in y2 (rows 50000..50047 zeroed by gemm)

typedef unsigned int   u32;
typedef unsigned short u16;
typedef __attribute__((ext_vector_type(4))) float f32x4;
typedef __attribute__((ext_vector_type(8))) short s16x8;

__device__ inline u16 f2bf(float f) {
  __hip_bfloat16 h = __float2bfloat16(f);
  return *reinterpret_cast<u16*>(&h);
}

// ---------------- W -> WT bf16 pre-swizzled + gcursor init (fused) ----------------
__global__ __launch_bounds__(256) void k_prep(const float* __restrict__ W,
                                              u16* __restrict__ wts,
                                              int* __restrict__ gcursor) {
  __shared__ float T[32 * 132];
  int t = threadIdx.x;
  int gi = blockIdx.x * 256 + t;
  if (gi < NB) gcursor[gi] = gi * BSTRIDE;
  int c0 = blockIdx.x * 32;
#pragma unroll
  for (int i = 0; i < 16; ++i) {
    int idx = i * 256 + t;            // 4096 = 128k x 32c
    int k = idx >> 5;
    int cc = idx & 31;
    T[cc * 132 + k] = W[k * 128 + c0 + cc];
  }
  __syncthreads();
#pragma unroll
  for (int i = 0; i < 2; ++i) {
    int idx = i * 256 + t;            // 512 = 32c x 16 chunks
    int cc = idx >> 4;
    int kc = idx & 15;
    int c = c0 + cc;
    int kbase = kc * 8;
    u32 p[4];
#pragma unroll
    for (int u = 0; u < 4; ++u) {
      float a = T[cc * 132 + kbase + 2 * u];
      float b = T[cc * 132 + kbase + 2 * u + 1];
      p[u] = (u32)f2bf(a) | ((u32)f2bf(b) << 16);
    }
    int off = c * 256 + ((kbase * 2) ^ ((c & 15) << 4));
    *(uint4*)((char*)wts + off) = make_uint4(p[0], p[1], p[2], p[3]);
  }
}

// ---------------- bin pass A: edges -> bucket regions (r,c packed u32), int4 loads ----------------
__global__ __launch_bounds__(256) void k_binA(const int* __restrict__ erow,
                                              const int* __restrict__ ecol,
                                              int* __restrict__ gcursor,
                                              u32* __restrict__ binned) {
  __shared__ int hist[NB];
  __shared__ int lcur[NB];
  int t = threadIdx.x;
  for (int b = t; b < NB; b += 256) hist[b] = 0;
  __syncthreads();
  int base = blockIdx.x * TILE;
  u32 v[EPT];
#pragma unroll
  for (int k = 0; k < 8; ++k) {
    int e4 = base + k * 1024 + t * 4;   // EDGES % 4 == 0 -> full int4 in-bounds when e4 < EDGES
    if (e4 < EDGES) {
      int4 rr = *(const int4*)&erow[e4];
      int4 cc = *(const int4*)&ecol[e4];
      v[k * 4 + 0] = ((u32)rr.x << 16) | (u32)cc.x;
      v[k * 4 + 1] = ((u32)rr.y << 16) | (u32)cc.y;
      v[k * 4 + 2] = ((u32)rr.z << 16) | (u32)cc.z;
      v[k * 4 + 3] = ((u32)rr.w << 16) | (u32)cc.w;
      atomicAdd(&hist[(u32)rr.x >> 7], 1);
      atomicAdd(&hist[(u32)rr.y >> 7], 1);
      atomicAdd(&hist[(u32)rr.z >> 7], 1);
      atomicAdd(&hist[(u32)rr.w >> 7], 1);
    } else {
      v[k * 4 + 0] = 0xffffffffu;
      v[k * 4 + 1] = 0xffffffffu;
      v[k * 4 + 2] = 0xffffffffu;
      v[k * 4 + 3] = 0xffffffffu;
    }
  }
  __syncthreads();
  for (int b = t; b < NB; b += 256) {
    int h = hist[b];
    lcur[b] = h ? atomicAdd(&gcursor[b], h) : 0;
  }
  __syncthreads();
#pragma unroll
  for (int k = 0; k < EPT; ++k) {
    if (v[k] != 0xffffffffu) {
      int b = (int)(v[k] >> 23);
      int pos = atomicAdd(&lcur[b], 1);
      if (pos < (b + 1) * BSTRIDE) binned[pos] = v[k];   // overflow clamp (never hit)
    }
  }
}

// ---------------- bin pass B: single read, LDS-staged node sort, coalesced cols write ----------------
__global__ __launch_bounds__(256) void k_binB(const u32* __restrict__ binned,
                                              const int* __restrict__ gcur,
                                              int2* __restrict__ rp2,
                                              float* __restrict__ dis,
                                              u16* __restrict__ cols) {
  __shared__ int cnt[128];
  __shared__ int sc[128];
  __shared__ int lcur[128];
  __shared__ u16 stage[BSTRIDE];     // 9216 B
  int b = blockIdx.x;
  int t = threadIdx.x;
  int n0 = b << 7;
  int s = b * BSTRIDE;
  int e = gcur[b];
  if (e > s + BSTRIDE) e = s + BSTRIDE;
  int cntE = e - s;
  if (t < 128) cnt[t] = 0;
  __syncthreads();
  // hold this thread's edges in registers (static indices), count per node
  u32 held[18];                      // BSTRIDE/256 = 18
#pragma unroll
  for (int k = 0; k < 18; ++k) {
    int j = s + t + k * 256;
    u32 v = (j < e) ? binned[j] : 0xffffffffu;   // r<50000 -> top half never 0xffff
    held[k] = v;
    if (v != 0xffffffffu) atomicAdd(&cnt[(int)(v >> 16) - n0], 1);
  }
  __syncthreads();
  if (t < 128) sc[t] = cnt[t];
  __syncthreads();
  for (int off = 1; off < 128; off <<= 1) {
    int tmp = (t >= off && t < 128) ? sc[t - off] : 0;
    __syncthreads();
    if (t < 128) sc[t] += tmp;
    __syncthreads();
  }
  if (t < 128) {
    int n = n0 + t;
    if (n < NODES) {
      int lexcl = sc[t] - cnt[t];              // local (within bucket)
      rp2[n] = make_int2(s + lexcl, s + lexcl + cnt[t]);
      lcur[t] = lexcl;
      dis[n] = rsqrtf((float)cnt[t]);
    }
  }
  __syncthreads();
#pragma unroll
  for (int k = 0; k < 18; ++k) {
    u32 v = held[k];
    if (v != 0xffffffffu) {
      int pos = atomicAdd(&lcur[(int)(v >> 16) - n0], 1);
      stage[pos] = (u16)(v & 0xffffu);
    }
  }
  __syncthreads();
  // coalesced copy stage[0..cntE) -> cols[s..); one extra u16 into the unused gap is harmless
  {
    u32* dst = (u32*)(cols + s);               // s even -> 4B aligned
    const u32* src = (const u32*)stage;
    int nw = (cntE + 1) >> 1;
    for (int i = t; i < nw; i += 256) dst[i] = src[i];
  }
}

// ---------------- y2 = diag(dis) * (x @ W) via MFMA, stored bf16 (pad rows zeroed) ----------------
__global__ __launch_bounds__(256) void k_gemm(const float* __restrict__ x,
                                              const u16* __restrict__ wts,
                                              const float* __restrict__ dis,
                                              u16* __restrict__ y2) {
  __shared__ u16 xs[64 * 128];
  __shared__ u16 ws[128 * 128];
  const int t = threadIdx.x;
  const int bb = blockIdx.x * 64;

  {
    const uint4* src = (const uint4*)wts;
    uint4* dst = (uint4*)ws;
#pragma unroll
    for (int i = 0; i < 8; ++i) dst[i * 256 + t] = src[i * 256 + t];
  }
  {
#pragma unroll
    for (int i = 0; i < 8; ++i) {
      int goff = i * 4096 + t * 16;
      int row = goff >> 9;
      int gr = bb + row;
      float4 v = make_float4(0.f, 0.f, 0.f, 0.f);
      if (gr < NODES) v = *(const float4*)((const char*)x + (size_t)gr * 512 + (goff & 511));
      u32 lo = (u32)f2bf(v.x) | ((u32)f2bf(v.y) << 16);
      u32 hi = (u32)f2bf(v.z) | ((u32)f2bf(v.w) << 16);
      int colb = (goff & 511) >> 1;
      int off = row * 256 + (colb ^ ((row & 15) << 4));
      *(uint2*)((char*)xs + off) = make_uint2(lo, hi);
    }
  }
  __syncthreads();

  const int w = t >> 6, l = t & 63, m = l & 15, g = l >> 4;
  f32x4 acc[8];
#pragma unroll
  for (int j = 0; j < 8; ++j) acc[j] = (f32x4)0.0f;

  const char* xb = (const char*)xs;
  const char* wb = (const char*)ws;
  const int arow = w * 16 + m;
#pragma unroll
  for (int s = 0; s < 4; ++s) {
    int kx = (g * 16 + s * 64) ^ (m << 4);
    s16x8 a = *(const s16x8*)(xb + arow * 256 + kx);
#pragma unroll
    for (int j = 0; j < 8; ++j) {
      s16x8 b = *(const s16x8*)(wb + (j * 16 + m) * 256 + kx);
      acc[j] = __builtin_amdgcn_mfma_f32_16x16x32_bf16(a, b, acc[j], 0, 0, 0);
    }
  }

  // epilogue: scale by dis[row]; rows >= NODES (up to 50047) store ZERO -> zero sentinel rows
  int rbase = bb + w * 16 + g * 4;
  float4 d4 = *(const float4*)&dis[rbase];   // dis region padded past 50000 (garbage ok, masked below)
#pragma unroll
  for (int j = 0; j < 8; ++j) {
#pragma unroll
    for (int r = 0; r < 4; ++r) {
      int gr = rbase + r;
      float dv = (r == 0) ? d4.x : (r == 1) ? d4.y : (r == 2) ? d4.z : d4.w;
      float val = (gr < NODES) ? acc[j][r] * dv : 0.0f;
      y2[(size_t)gr * 128 + j * 16 + m] = f2bf(val);   // gr <= 50047 < 50048 rows: in-bounds
    }
  }
}

// ---------------- aggregation: 16 edges in flight per wave (4 groups x 4-deep pipeline) ----------------
// 16 lanes x 16B per edge row; zero-row sentinel makes loads+accumulates unconditional.
__global__ __launch_bounds__(256) void k_agg(const u16* __restrict__ y2,
                                             const int2* __restrict__ rp2,
                                             const u16* __restrict__ cols,
                                             const float* __restrict__ dis,
                                             const float* __restrict__ bias,
                                             float* __restrict__ out) {
  int node = (blockIdx.x * 256 + threadIdx.x) >> 6;
  int l = threadIdx.x & 63;
  if (node >= NODES) return;
  int q = l >> 4;          // which edge within a group of 4
  int m = l & 15;          // 16B chunk within the 256B row
  int2 rr = rp2[node];
  int s = rr.x;
  int e = rr.y;

  float a0 = 0.f, a1 = 0.f, a2 = 0.f, a3 = 0.f;
  float a4 = 0.f, a5 = 0.f, a6 = 0.f, a7 = 0.f;
  const uint4* yb = (const uint4*)y2;

  // prefetch cols for the first 16-edge batch
  int c0 = (s + q      < e) ? (int)cols[s + q]      : ZROW;
  int c1 = (s + 4 + q  < e) ? (int)cols[s + 4 + q]  : ZROW;
  int c2 = (s + 8 + q  < e) ? (int)cols[s + 8 + q]  : ZROW;
  int c3 = (s + 12 + q < e) ? (int)cols[s + 12 + q] : ZROW;

  for (int jb = s; jb < e; jb += 16) {
    int nb = jb + 16;
    int d0 = (nb + q      < e) ? (int)cols[nb + q]      : ZROW;
    int d1 = (nb + 4 + q  < e) ? (int)cols[nb + 4 + q]  : ZROW;
    int d2 = (nb + 8 + q  < e) ? (int)cols[nb + 8 + q]  : ZROW;
    int d3 = (nb + 12 + q < e) ? (int)cols[nb + 12 + q] : ZROW;
    uint4 v0 = yb[c0 * 16 + m];
    uint4 v1 = yb[c1 * 16 + m];
    uint4 v2 = yb[c2 * 16 + m];
    uint4 v3 = yb[c3 * 16 + m];
#define ACC(v)                                   \
    a0 += __uint_as_float((v).x << 16);          \
    a1 += __uint_as_float((v).x & 0xffff0000u);  \
    a2 += __uint_as_float((v).y << 16);          \
    a3 += __uint_as_float((v).y & 0xffff0000u);  \
    a4 += __uint_as_float((v).z << 16);          \
    a5 += __uint_as_float((v).z & 0xffff0000u);  \
    a6 += __uint_as_float((v).w << 16);          \
    a7 += __uint_as_float((v).w & 0xffff0000u);
    ACC(v0) ACC(v1) ACC(v2) ACC(v3)
#undef ACC
    c0 = d0; c1 = d1; c2 = d2; c3 = d3;
  }

  // reduce across the 4 groups (lane bits 4,5)
  a0 += __shfl_xor(a0, 16); a0 += __shfl_xor(a0, 32);
  a1 += __shfl_xor(a1, 16); a1 += __shfl_xor(a1, 32);
  a2 += __shfl_xor(a2, 16); a2 += __shfl_xor(a2, 32);
  a3 += __shfl_xor(a3, 16); a3 += __shfl_xor(a3, 32);
  a4 += __shfl_xor(a4, 16); a4 += __shfl_xor(a4, 32);
  a5 += __shfl_xor(a5, 16); a5 += __shfl_xor(a5, 32);
  a6 += __shfl_xor(a6, 16); a6 += __shfl_xor(a6, 32);
  a7 += __shfl_xor(a7, 16); a7 += __shfl_xor(a7, 32);

  float di = (e > s) ? dis[node] : 0.0f;
  if (q < 2) {
    float r0 = q ? a4 : a0;
    float r1 = q ? a5 : a1;
    float r2 = q ? a6 : a2;
    float r3 = q ? a7 : a3;
    float4 bb = *(const float4*)&bias[m * 8 + q * 4];
    f32x4 o;
    o[0] = bb.x + di * r0;
    o[1] = bb.y + di * r1;
    o[2] = bb.z + di * r2;
    o[3] = bb.w + di * r3;
    __builtin_nontemporal_store(o, (f32x4*)&out[(size_t)node * 128 + m * 8 + q * 4]);
  }
}

extern "C" void kernel_launch(void* const* d_in, const int* in_sizes, int n_in,
                              void* d_out, int out_size, void* d_ws, size_t ws_size,
                              hipStream_t stream) {
  const float* x    = (const float*)d_in[0];
  const float* W    = (const float*)d_in[1];
  const float* bias = (const float*)d_in[2];
  const int*   erow = (const int*)d_in[3];
  const int*   ecol = (const int*)d_in[4];
  float* out = (float*)d_out;

  char* ws = (char*)d_ws;
  int*   gcursor = (int*)(ws + 0);          // 1.6 KB
  int2*  rp2     = (int2*)(ws + 4096);      // 400 KB
  float* dis     = (float*)(ws + 409600);   // 200 KB (+pad, gemm reads to 50048)
  u16*   wts     = (u16*)(ws + 614400);     // 32 KB
  u32*   binned  = (u32*)(ws + 655360);     // 391*4608*4 = 7,206,912 B
  u16*   cols    = (u16*)(ws + 7864320);    // 391*4608*2 = 3,603,456 B (+1KB slack)
  u16*   y2      = (u16*)(ws + 11468800);   // 50048 rows * 256 B = 12,812,288 B

  k_prep<<<4, 256, 0, stream>>>(W, wts, gcursor);
  k_binA<<<NTILES, 256, 0, stream>>>(erow, ecol, gcursor, binned);
  k_binB<<<NB, 256, 0, stream>>>(binned, gcursor, rp2, dis, cols);
  k_gemm<<<(NODES + 63) / 64, 256, 0, stream>>>(x, wts, dis, y2);
  k_agg<<<(NODES * 64 + 255) / 256, 256, 0, stream>>>(y2, rp2, cols, dis, bias, out);
}